// Round 2
// baseline (141.783 us; speedup 1.0000x reference)
//
#include <hip/hip_runtime.h>

// GAS(1,1) Gaussian-copula log-likelihood scan, T = 2^20.
//
// R4 (resubmit — R1 bench hit GPUAcquisitionTimeout, never ran):
// single fused kernel, NO workspace.
//  - R3 analysis: dur 96us = ws-poison fill 41us (256 MiB fillBufferAligned,
//    the only >40us dispatches in rocprof) + scan ~36us + prep ~4us + gaps.
//    Dropping all d_ws use removes prep and (if the harness poison is
//    conditional on ws) the 41us fill.
//  - ndtri fused into the scan: at 1 wave/SIMD the scan is chain-latency
//    bound (~320 cyc/step measured vs ~120 chain floor) -> idle issue slots
//    absorb the 2 ndtri/step recompute. Warm windows of a wave overlap 94%
//    (~10 KB sliding footprint) -> L1-resident, no HBM cost.
//  - exp2-domain state F = 2*log2(e)*f (recurrence is linear in f, folds
//    into constants) deletes one chain mul before v_exp.
//  - dll = ((rho+xy)*D - rho*z) * invD^2: rcp(D) runs parallel to the
//    numerator; post-dll tail is mul -> fma -> rsq -> fma with
//    0.99s+1e-8 / 0.99s / gg*0.1 / gg*kappa*A hoisted off-chain.
//  - depth-2 raw prefetch + ndtri conversion pipelined 1 group ahead.
// Error model unchanged: W=256, same ndtri_fast bits, same clamp; R3
// absmax 64.0 expected to hold (contractive recurrence damps rounding).

#define T_LEN     (1 << 20)
#define CHUNK_LEN 16
#define NCHUNK    (T_LEN / CHUNK_LEN)   // 65536 threads -> 1024 waves -> 1/SIMD
#define WARM      256                   // multiple of 16

#if __has_builtin(__builtin_amdgcn_exp2f)
#define EXP2F(x) __builtin_amdgcn_exp2f(x)
#else
#define EXP2F(x) __expf(0.69314718056f * (x))
#endif

// ---------------- ndtri via Giles' single-precision erfinv ----------------
// (bit-identical to R3's prep version: keeps the calibrated error model)
__device__ __forceinline__ float ndtri_fast(float u) {
    float t = 2.0f * u - 1.0f;
    float w = -__logf(fmaxf(4.0f * u * (1.0f - u), 1e-38f));
    float p;
    if (w < 5.0f) {
        w = w - 2.5f;
        p =            2.81022636e-08f;
        p = fmaf(p, w, 3.43273939e-07f);
        p = fmaf(p, w, -3.5233877e-06f);
        p = fmaf(p, w, -4.39150654e-06f);
        p = fmaf(p, w, 0.00021858087f);
        p = fmaf(p, w, -0.00125372503f);
        p = fmaf(p, w, -0.00417768164f);
        p = fmaf(p, w, 0.246640727f);
        p = fmaf(p, w, 1.50140941f);
    } else {
        w = __builtin_amdgcn_sqrtf(w) - 3.0f;
        p =            -0.000200214257f;
        p = fmaf(p, w, 0.000100950558f);
        p = fmaf(p, w, 0.00134934322f);
        p = fmaf(p, w, -0.00367342844f);
        p = fmaf(p, w, 0.00573950773f);
        p = fmaf(p, w, -0.0076224613f);
        p = fmaf(p, w, 0.00943887047f);
        p = fmaf(p, w, 1.00167406f);
        p = fmaf(p, w, 2.83297682f);
    }
    return 1.41421356237f * p * t;
}

// (u,v) -> (x^2+y^2, x*y)
__device__ __forceinline__ void cop_pair(float uu, float vv,
                                         float& sq, float& xy) {
    float x = ndtri_fast(fminf(fmaxf(uu, 1e-9f), 1.0f - 1e-9f));
    float y = ndtri_fast(fminf(fmaxf(vv, 1e-9f), 1.0f - 1e-9f));
    sq = fmaf(x, x, y * y);
    xy = x * y;
}

// ---------------- one GAS step in exp2-domain ------------------------------
// State: F = KAP*f (KAP = 2*log2 e), s = EMA of score^2.
// Chain: exp2 -> +1 -> rcp -> fma(rho) -> fma(D) -> rcp -> mul(invD2)
//        -> mul(dll) -> mul(sc01) -> fma(t) -> rsq -> fma(F')   (~12 deps)
template <bool LL>
__device__ __forceinline__ float gas_stepF(float sq, float xy,
                                           float& F, float& s,
                                           float OmegaF, float AK, float B) {
    float E    = EXP2F(F);                            // e^{2f} = 2^F
    float r    = __builtin_amdgcn_rcpf(E + 1.0f);
    float rho  = fmaf(-1.998f, r, 0.999f);            // 0.999*tanh(f)
    float n2r  = fmaf(3.996f, r, -1.998f);            // -2*rho      (parallel)
    float gg   = 3.996f * r * (1.0f - r);             // 0.999*(1-th^2)  (par)
    float D    = fmaf(-rho, rho, 1.0f);               // +1e-8 below ulp
    float invD = __builtin_amdgcn_rcpf(D);
    float z    = fmaf(n2r, xy, sq);                   // sq - 2 rho x y  (par)
    float rxyD = (rho + xy) * D;                      // parallel with rcp
    float N    = fmaf(-rho, z, rxyD);                 // (rho+xy)D - rho z
    float invD2 = invD * invD;
    float dll  = N * invD2;                           // dll/drho
    // off-chain precomputes (issue in chain gaps)
    float base = fmaf(B, F - OmegaF, OmegaF);
    float cpre = fmaf(0.99f, s, 1e-8f);
    float s99  = 0.99f * s;
    float g01  = gg * 0.1f;                           // 0.1*gg
    float gA   = gg * AK;                             // KAP*A*gg
    // chain tail
    float sc01 = dll * g01;                           // 0.1*score
    float scA  = dll * gA;                            // KAP*A*score (parallel)
    float t    = fmaf(sc01, sc01, cpre);              // snew + 1e-8
    float inv  = __builtin_amdgcn_rsqf(t);
    s          = fmaf(sc01, sc01, s99);               // snew
    F          = fmaf(scA, inv, base);                // KAP*f_new
    if (LL) {
        float zi = z * invD;
        return fmaf(-0.5f, __logf(D), 0.5f * (sq - zi));
    }
    return 0.0f;
}

// ---------------- fused kernel: ndtri + chunked warm-up scan ---------------
__launch_bounds__(256, 1)
__global__ void scan_kernel(const float4* __restrict__ u4,
                            const float4* __restrict__ v4,
                            const float* __restrict__ p_omega,
                            const float* __restrict__ p_A,
                            const float* __restrict__ p_Blogit,
                            float* __restrict__ out) {
    const int c = blockIdx.x * blockDim.x + threadIdx.x;   // chunk id
    const float omega = p_omega[0];
    const float A     = p_A[0];
    const float B     = 1.0f / (1.0f + __expf(-p_Blogit[0]));
    const float KAP   = 2.8853900817779268f;               // 2*log2(e)
    const float OmegaF = omega * KAP;
    const float AK     = A * KAP;

    const int t0     = c * CHUNK_LEN - WARM;
    const int tstart = (t0 < 0) ? 0 : t0;            // early chunks: exact init
    const int warm   = (t0 < 0) ? (c * CHUNK_LEN) : WARM;   // multiple of 16
    const int Gw     = warm >> 2;                    // warm groups of 4 steps

    const float4* __restrict__ pu = u4 + (tstart >> 2);
    const float4* __restrict__ pv = v4 + (tstart >> 2);

    // ---- live tile raw preload (16 steps = 4 groups), issued first --------
    float4 lu0 = pu[Gw + 0], lv0 = pv[Gw + 0];
    float4 lu1 = pu[Gw + 1], lv1 = pv[Gw + 1];
    float4 lu2 = pu[Gw + 2], lv2 = pv[Gw + 2];
    float4 lu3 = pu[Gw + 3], lv3 = pv[Gw + 3];

    // convert live tile now (frees the raw regs; off the warm chain)
    float lsq[16], lxy[16];
    cop_pair(lu0.x, lv0.x, lsq[0],  lxy[0]);
    cop_pair(lu0.y, lv0.y, lsq[1],  lxy[1]);
    cop_pair(lu0.z, lv0.z, lsq[2],  lxy[2]);
    cop_pair(lu0.w, lv0.w, lsq[3],  lxy[3]);
    cop_pair(lu1.x, lv1.x, lsq[4],  lxy[4]);
    cop_pair(lu1.y, lv1.y, lsq[5],  lxy[5]);
    cop_pair(lu1.z, lv1.z, lsq[6],  lxy[6]);
    cop_pair(lu1.w, lv1.w, lsq[7],  lxy[7]);
    cop_pair(lu2.x, lv2.x, lsq[8],  lxy[8]);
    cop_pair(lu2.y, lv2.y, lsq[9],  lxy[9]);
    cop_pair(lu2.z, lv2.z, lsq[10], lxy[10]);
    cop_pair(lu2.w, lv2.w, lsq[11], lxy[11]);
    cop_pair(lu3.x, lv3.x, lsq[12], lxy[12]);
    cop_pair(lu3.y, lv3.y, lsq[13], lxy[13]);
    cop_pair(lu3.z, lv3.z, lsq[14], lxy[14]);
    cop_pair(lu3.w, lv3.w, lsq[15], lxy[15]);

    float F = OmegaF, s = 1.0f;

    // ---- warm loop: depth-2 raw prefetch, ndtri pipelined 1 group ahead ---
    if (Gw > 0) {
        float4 cu = pu[0], cv = pv[0];
        int g1 = (Gw > 1) ? 1 : 0;
        float4 nu = pu[g1], nv = pv[g1];
        float csq0, cxy0, csq1, cxy1, csq2, cxy2, csq3, cxy3;
        cop_pair(cu.x, cv.x, csq0, cxy0);
        cop_pair(cu.y, cv.y, csq1, cxy1);
        cop_pair(cu.z, cv.z, csq2, cxy2);
        cop_pair(cu.w, cv.w, csq3, cxy3);
        for (int g = 0; g < Gw; ++g) {
            int gf = g + 2; gf = (gf < Gw) ? gf : (Gw - 1);
            float4 fu = pu[gf], fv = pv[gf];          // issue loads early
            float nsq0, nxy0, nsq1, nxy1, nsq2, nxy2, nsq3, nxy3;
            cop_pair(nu.x, nv.x, nsq0, nxy0);         // independent of chain
            cop_pair(nu.y, nv.y, nsq1, nxy1);
            cop_pair(nu.z, nv.z, nsq2, nxy2);
            cop_pair(nu.w, nv.w, nsq3, nxy3);
            gas_stepF<false>(csq0, cxy0, F, s, OmegaF, AK, B);
            gas_stepF<false>(csq1, cxy1, F, s, OmegaF, AK, B);
            gas_stepF<false>(csq2, cxy2, F, s, OmegaF, AK, B);
            gas_stepF<false>(csq3, cxy3, F, s, OmegaF, AK, B);
            csq0 = nsq0; cxy0 = nxy0; csq1 = nsq1; cxy1 = nxy1;
            csq2 = nsq2; cxy2 = nxy2; csq3 = nsq3; cxy3 = nxy3;
            nu = fu; nv = fv;
        }
    }

    // ---- live loop: 16 steps from converted registers ---------------------
    float acc = 0.0f;
#pragma unroll
    for (int i = 0; i < 16; ++i)
        acc += gas_stepF<true>(lsq[i], lxy[i], F, s, OmegaF, AK, B);

    // block reduction -> one atomicAdd per block
    __shared__ float red[256];
    red[threadIdx.x] = acc;
    __syncthreads();
    for (int off = 128; off > 0; off >>= 1) {
        if (threadIdx.x < off) red[threadIdx.x] += red[threadIdx.x + off];
        __syncthreads();
    }
    if (threadIdx.x == 0) atomicAdd(out, red[0]);
}

extern "C" void kernel_launch(void* const* d_in, const int* in_sizes, int n_in,
                              void* d_out, int out_size, void* d_ws, size_t ws_size,
                              hipStream_t stream) {
    (void)in_sizes; (void)n_in; (void)out_size; (void)d_ws; (void)ws_size;
    const float* u       = (const float*)d_in[0];
    const float* v       = (const float*)d_in[1];
    const float* omega   = (const float*)d_in[2];
    const float* A       = (const float*)d_in[3];
    const float* B_logit = (const float*)d_in[4];
    float*       out     = (float*)d_out;

    // out must be 0 before any block's atomicAdd (graph-capturable memset)
    hipMemsetAsync(out, 0, sizeof(float), stream);

    scan_kernel<<<NCHUNK / 256, 256, 0, stream>>>(
        (const float4*)u, (const float4*)v, omega, A, B_logit, out);
}

// Round 3
// 106.649 us; speedup vs baseline: 1.3294x; 1.3294x over previous
//
#include <hip/hip_runtime.h>

// GAS(1,1) Gaussian-copula log-likelihood scan, T = 2^20.
//
// R5: back to R3's two-kernel structure (fused ndtri was a 2.4x scan
// regression: log/sqrt contend for the transcendental pipe that the chain
// lives on). New: single-transcendental chain.
//   R4 evidence: total - scan = ~56us fixed harness tax (256MiB ws poison
//   fill runs unconditionally + gaps). Only prep+scan are controllable.
//   R3 scan L=317 cyc/step fits chain exp2->rcp->rcp->rsq + 8 fma deps
//   with transcendental dep latency T~70. This version keeps ONLY exp2:
//   - Q=(E+1)^2*D, R=(E+1)^2 are polynomials in E; score =
//     3.996E*[(rho+xy)*invQ - 0.999*M*P*z*invQ^2]  (invR only enters rho).
//   - invQ/invR: double-Newton from previous step's value (Q,R move
//     ~15%/step -> err ~1e-3); wave-uniform __any guard reseeds with
//     exact v_rcp on rare big jumps (also self-heals).
//   - 1/sqrt(s+1e-8): carried sigma + one Newton (s moves <=~1%/step),
//     folded as w = 1.5 + nh2*t;  F = fma(scAp, w, base).
//   Chain ~ T+60 ~ 140 cyc/step (vs 317). Newton transients perturb f by
//   ~1e-3/step, damped 0.95/step: absmax 64 -> expect ~70-90 (tol ~142).

#define T_LEN     (1 << 20)
#define CHUNK_LEN 16
#define NCHUNK    (T_LEN / CHUNK_LEN)   // 65536 threads -> 1024 waves -> 1/SIMD
#define WARM      256                   // multiple of 16

#if __has_builtin(__builtin_amdgcn_exp2f)
#define EXP2F(x) __builtin_amdgcn_exp2f(x)
#else
#define EXP2F(x) __expf(0.69314718056f * (x))
#endif

// ---------------- ndtri via Giles' single-precision erfinv ----------------
// (bit-identical to R3: keeps the calibrated warm-up error model)
__device__ __forceinline__ float ndtri_fast(float u) {
    float t = 2.0f * u - 1.0f;
    float w = -__logf(fmaxf(4.0f * u * (1.0f - u), 1e-38f));
    float p;
    if (w < 5.0f) {
        w = w - 2.5f;
        p =            2.81022636e-08f;
        p = fmaf(p, w, 3.43273939e-07f);
        p = fmaf(p, w, -3.5233877e-06f);
        p = fmaf(p, w, -4.39150654e-06f);
        p = fmaf(p, w, 0.00021858087f);
        p = fmaf(p, w, -0.00125372503f);
        p = fmaf(p, w, -0.00417768164f);
        p = fmaf(p, w, 0.246640727f);
        p = fmaf(p, w, 1.50140941f);
    } else {
        w = __builtin_amdgcn_sqrtf(w) - 3.0f;
        p =            -0.000200214257f;
        p = fmaf(p, w, 0.000100950558f);
        p = fmaf(p, w, 0.00134934322f);
        p = fmaf(p, w, -0.00367342844f);
        p = fmaf(p, w, 0.00573950773f);
        p = fmaf(p, w, -0.0076224613f);
        p = fmaf(p, w, 0.00943887047f);
        p = fmaf(p, w, 1.00167406f);
        p = fmaf(p, w, 2.83297682f);
    }
    return 1.41421356237f * p * t;
}

// ---------------- kernel 1: precompute (x^2+y^2, -2xy); also zero out ------
__global__ void prep_kernel(const float4* __restrict__ u4,
                            const float4* __restrict__ v4,
                            float4* __restrict__ sp4,
                            float* __restrict__ out) {
    int i = blockIdx.x * blockDim.x + threadIdx.x;   // i < T_LEN/4
    if (i == 0) out[0] = 0.0f;                       // replaces memset dispatch
    float4 uu = u4[i];
    float4 vv = v4[i];
    float x0 = ndtri_fast(fminf(fmaxf(uu.x, 1e-9f), 1.0f - 1e-9f));
    float x1 = ndtri_fast(fminf(fmaxf(uu.y, 1e-9f), 1.0f - 1e-9f));
    float x2 = ndtri_fast(fminf(fmaxf(uu.z, 1e-9f), 1.0f - 1e-9f));
    float x3 = ndtri_fast(fminf(fmaxf(uu.w, 1e-9f), 1.0f - 1e-9f));
    float y0 = ndtri_fast(fminf(fmaxf(vv.x, 1e-9f), 1.0f - 1e-9f));
    float y1 = ndtri_fast(fminf(fmaxf(vv.y, 1e-9f), 1.0f - 1e-9f));
    float y2 = ndtri_fast(fminf(fmaxf(vv.z, 1e-9f), 1.0f - 1e-9f));
    float y3 = ndtri_fast(fminf(fmaxf(vv.w, 1e-9f), 1.0f - 1e-9f));
    float4 o0, o1;
    o0.x = fmaf(x0, x0, y0 * y0);  o0.y = -2.0f * x0 * y0;
    o0.z = fmaf(x1, x1, y1 * y1);  o0.w = -2.0f * x1 * y1;
    o1.x = fmaf(x2, x2, y2 * y2);  o1.y = -2.0f * x2 * y2;
    o1.z = fmaf(x3, x3, y3 * y3);  o1.w = -2.0f * x3 * y3;
    sp4[2 * i]     = o0;
    sp4[2 * i + 1] = o1;
}

// ---------------- one GAS step, single-transcendental chain ----------------
// State: F = KAP*f; s = EMA of score^2; sig ~ 1/sqrt(s+1e-8);
//        nh2 = -0.5*sig^2; cs = cAK*sig; invQ ~ 1/Q, invR ~ 1/R (tracked).
// Chain: exp2 -> poly(Q) -> 2xNewton(invQ) -> core products -> inner
//        -> scg -> t -> w -> F                     (~T + 60 cyc)
template <bool LL>
__device__ __forceinline__ float gas_step(float sq, float m2p,
                                          float& F, float& s, float& sig,
                                          float& nh2, float& cs,
                                          float& invQ, float& invR,
                                          float OmegaF, float B, float cAK) {
    float E   = EXP2F(F);                         // e^{2f} = 2^F
    float P   = E + 1.0f;
    float Mm  = E - 1.0f;
    float a_  = fmaf(-0.999f, Mm, P);             // P - 0.999M
    float b_  = fmaf( 0.999f, Mm, P);             // P + 0.999M
    float Q   = a_ * b_;                          // P^2 - 0.999^2 M^2 = P^2 D
    float R   = P * P;
    float kMP = 0.999f * (Mm * P);                // rho * R  (exact product)

    // Newton refresh of invR/invQ from previous step's values.
    float eR = R * invR;
    float eQ = Q * invQ;
    if (__any(fabsf(eR - 1.0f) > 0.35f || fabsf(eQ - 1.0f) > 0.35f)) {
        invR = __builtin_amdgcn_rcpf(R);          // rare: big f-jump / reseed
        invQ = __builtin_amdgcn_rcpf(Q);
        eR = R * invR;
        eQ = Q * invQ;
    }
    float txR = invR + invR;
    float x1R = fmaf(-eR, invR, txR);             // Newton 1
    float e2R = R * x1R;
    float tx2R = x1R + x1R;
    invR = fmaf(-e2R, x1R, tx2R);                 // Newton 2
    float txQ = invQ + invQ;
    float x1Q = fmaf(-eQ, invQ, txQ);
    float e2Q = Q * x1Q;
    float tx2Q = x1Q + x1Q;
    invQ = fmaf(-e2Q, x1Q, tx2Q);

    // core: score = 3.996E * [ (rho+xy)*invQ - kMP*z*invQ^2 ]
    float rho  = kMP * invR;                      // 0.999*tanh(f)
    float z    = fmaf(rho, m2p, sq);              // sq - 2 rho x y
    float rpxy = fmaf(-0.5f, m2p, rho);           // rho + x*y
    float iQ2  = invQ * invQ;
    float t1   = rpxy * invQ;
    float zk   = z * kMP;
    float t2   = zk * iQ2;
    float inner = t1 - t2;

    // tail (4 levels after inner)
    float pe   = 0.3996f * E;                     // 0.1 * 3.996E   (early)
    float scg  = pe * inner;                      // 0.1 * score
    float c1   = cs * E;                          // cAK*sig_prev*E (early)
    float scAp = c1 * inner;                      // AK*score*sig_prev
    float cpre = fmaf(0.99f, s, 1e-8f);
    float s99  = 0.99f * s;
    float t    = fmaf(scg, scg, cpre);            // s_new + 1e-8
    float w    = fmaf(nh2, t, 1.5f);              // rsqrt Newton factor
    float base = fmaf(B, F - OmegaF, OmegaF);
    F = fmaf(scAp, w, base);                      // f' = base + A*score*sig_new

    // state updates (off the critical chain)
    s   = fmaf(scg, scg, s99);
    sig = sig * w;
    nh2 = -0.5f * (sig * sig);
    cs  = cAK * sig;

    if (LL) {
        float Dv  = Q * invR;                     // D
        float ziv = z * (R * invQ);               // z / D
        return fmaf(-0.5f, __logf(Dv), 0.5f * (sq - ziv));
    }
    return 0.0f;
}

// ---------------- kernel 2: chunked warm-up scan ---------------------------
__launch_bounds__(256, 1)
__global__ void scan_kernel(const float2* __restrict__ sp,
                            const float* __restrict__ p_omega,
                            const float* __restrict__ p_A,
                            const float* __restrict__ p_Blogit,
                            float* __restrict__ out) {
    const int c = blockIdx.x * blockDim.x + threadIdx.x;   // chunk id
    const float omega = p_omega[0];
    const float A     = p_A[0];
    const float B     = 1.0f / (1.0f + __expf(-p_Blogit[0]));
    const float KAP   = 2.8853900817779268f;               // 2*log2(e)
    const float OmegaF = omega * KAP;
    const float cAK    = A * KAP * 3.996f;

    const int t0     = c * CHUNK_LEN - WARM;
    const int tstart = (t0 < 0) ? 0 : t0;            // early chunks: exact init
    const int warm   = (t0 < 0) ? (c * CHUNK_LEN) : WARM;   // multiple of 16
    const int Gw     = warm >> 2;                    // warm groups of 4 steps

    const float4* __restrict__ pf = (const float4*)(sp + tstart);  // 16B aligned

    // Preload the full live tile (16 steps = 8 float4) before the warm loop.
    float4 l0 = pf[2 * Gw + 0], l1 = pf[2 * Gw + 1];
    float4 l2 = pf[2 * Gw + 2], l3 = pf[2 * Gw + 3];
    float4 l4 = pf[2 * Gw + 4], l5 = pf[2 * Gw + 5];
    float4 l6 = pf[2 * Gw + 6], l7 = pf[2 * Gw + 7];

    // state + exact reciprocal seeds at F = OmegaF
    float F = OmegaF, s = 1.0f;
    float sig = 1.0f, nh2 = -0.5f, cs = cAK;
    float E0 = EXP2F(F);
    float P0 = E0 + 1.0f, M0 = E0 - 1.0f;
    float R0 = P0 * P0;
    float Q0 = fmaf(-0.999f, M0, P0) * fmaf(0.999f, M0, P0);
    float invR = __builtin_amdgcn_rcpf(R0);
    float invQ = __builtin_amdgcn_rcpf(Q0);

    // ---- warm loop: no ll/log, next-group prefetch ----
    if (Gw > 0) {
        float4 a = pf[0], b = pf[1];
        for (int g = 0; g < Gw; ++g) {
            int gn = (g + 1 < Gw) ? (g + 1) : g;
            float4 na = pf[2 * gn];
            float4 nb = pf[2 * gn + 1];
            gas_step<false>(a.x, a.y, F, s, sig, nh2, cs, invQ, invR, OmegaF, B, cAK);
            gas_step<false>(a.z, a.w, F, s, sig, nh2, cs, invQ, invR, OmegaF, B, cAK);
            gas_step<false>(b.x, b.y, F, s, sig, nh2, cs, invQ, invR, OmegaF, B, cAK);
            gas_step<false>(b.z, b.w, F, s, sig, nh2, cs, invQ, invR, OmegaF, B, cAK);
            a = na; b = nb;
        }
    }

    // ---- live loop: 16 steps, fully unrolled from preloaded registers ----
    float acc;
    acc  = gas_step<true>(l0.x, l0.y, F, s, sig, nh2, cs, invQ, invR, OmegaF, B, cAK);
    acc += gas_step<true>(l0.z, l0.w, F, s, sig, nh2, cs, invQ, invR, OmegaF, B, cAK);
    acc += gas_step<true>(l1.x, l1.y, F, s, sig, nh2, cs, invQ, invR, OmegaF, B, cAK);
    acc += gas_step<true>(l1.z, l1.w, F, s, sig, nh2, cs, invQ, invR, OmegaF, B, cAK);
    acc += gas_step<true>(l2.x, l2.y, F, s, sig, nh2, cs, invQ, invR, OmegaF, B, cAK);
    acc += gas_step<true>(l2.z, l2.w, F, s, sig, nh2, cs, invQ, invR, OmegaF, B, cAK);
    acc += gas_step<true>(l3.x, l3.y, F, s, sig, nh2, cs, invQ, invR, OmegaF, B, cAK);
    acc += gas_step<true>(l3.z, l3.w, F, s, sig, nh2, cs, invQ, invR, OmegaF, B, cAK);
    acc += gas_step<true>(l4.x, l4.y, F, s, sig, nh2, cs, invQ, invR, OmegaF, B, cAK);
    acc += gas_step<true>(l4.z, l4.w, F, s, sig, nh2, cs, invQ, invR, OmegaF, B, cAK);
    acc += gas_step<true>(l5.x, l5.y, F, s, sig, nh2, cs, invQ, invR, OmegaF, B, cAK);
    acc += gas_step<true>(l5.z, l5.w, F, s, sig, nh2, cs, invQ, invR, OmegaF, B, cAK);
    acc += gas_step<true>(l6.x, l6.y, F, s, sig, nh2, cs, invQ, invR, OmegaF, B, cAK);
    acc += gas_step<true>(l6.z, l6.w, F, s, sig, nh2, cs, invQ, invR, OmegaF, B, cAK);
    acc += gas_step<true>(l7.x, l7.y, F, s, sig, nh2, cs, invQ, invR, OmegaF, B, cAK);
    acc += gas_step<true>(l7.z, l7.w, F, s, sig, nh2, cs, invQ, invR, OmegaF, B, cAK);

    // block reduction -> one atomicAdd per block
    __shared__ float red[256];
    red[threadIdx.x] = acc;
    __syncthreads();
    for (int off = 128; off > 0; off >>= 1) {
        if (threadIdx.x < off) red[threadIdx.x] += red[threadIdx.x + off];
        __syncthreads();
    }
    if (threadIdx.x == 0) atomicAdd(out, red[0]);
}

extern "C" void kernel_launch(void* const* d_in, const int* in_sizes, int n_in,
                              void* d_out, int out_size, void* d_ws, size_t ws_size,
                              hipStream_t stream) {
    (void)in_sizes; (void)n_in; (void)out_size; (void)ws_size;
    const float* u       = (const float*)d_in[0];
    const float* v       = (const float*)d_in[1];
    const float* omega   = (const float*)d_in[2];
    const float* A       = (const float*)d_in[3];
    const float* B_logit = (const float*)d_in[4];
    float*       out     = (float*)d_out;
    float2*      sp      = (float2*)d_ws;            // 8 MiB: (x^2+y^2, -2xy)

    prep_kernel<<<T_LEN / 4 / 256, 256, 0, stream>>>(
        (const float4*)u, (const float4*)v, (float4*)sp, out);
    scan_kernel<<<NCHUNK / 256, 256, 0, stream>>>(sp, omega, A, B_logit, out);
}